// Round 5
// baseline (340.557 us; speedup 1.0000x reference)
//
#include <hip/hip_runtime.h>
#include <hip/hip_cooperative_groups.h>

// Performer exp-kernel linear causal attention — single cooperative kernel.
// B=4 H=8 N=2048 D=64 fp32. Stabilization maxes cancel in the ratio (verified
// R4: absmax identical without them).
// Phase 1: per-chunk K'/V' staged in LDS (3 layouts), KV^T partial + Ksum -> ws
// grid.sync()
// Phase 2: parallel in-place exclusive scan over 32 chunks (register scan)
// grid.sync()
// Phase 3: out = (Q'.KVpref + masked(Q'K'^T).V) / denom, K'/V' still in LDS.
// 512 blocks x 256 thr, 2 chunks/block, ~59 KB LDS -> exactly 2 blocks/CU.

namespace cg = cooperative_groups;

#define NSEQ 2048
#define DD 64
#define CH 64
#define NC (NSEQ / CH)   // 32
#define BHN 32
#define NCHUNK (BHN * NC)   // 1024
#define EPSF 1e-8f
#define NRM 0.35355339059327373f   // 64^(-0.25)
#define C1 (NRM * 1.4426950408889634f)   // nrm * log2(e)

typedef short bf16x8 __attribute__((ext_vector_type(8)));
typedef float f32x4 __attribute__((ext_vector_type(4)));

__device__ __forceinline__ unsigned short f2bf(float f) {
  union { float f; unsigned u; } c; c.f = f;
  unsigned u = c.u + 0x7fffu + ((c.u >> 16) & 1u);
  return (unsigned short)(u >> 16);
}
__device__ __forceinline__ float bf2f(unsigned short s) {
  union { unsigned u; float f; } c; c.u = ((unsigned)s) << 16;
  return c.f;
}

__global__ __launch_bounds__(256) void perf_fused(const float* __restrict__ qg,
                                                  const float* __restrict__ kg,
                                                  const float* __restrict__ vg,
                                                  float* __restrict__ ksum,
                                                  unsigned short* __restrict__ kvws,
                                                  float* __restrict__ out) {
  // Per chunk: Kt = K'^T [e][j] (A-op for KV partial), Kb = K' [j][e] (B-op for
  // S), Vt = V^T [f][j] (B-op for KV partial and PV). 72-short pitch.
  __shared__ __align__(16) unsigned short Kt[2][DD * 72];   // 2 x 9 KB
  __shared__ __align__(16) unsigned short Kb[2][CH * 72];   // 2 x 9 KB
  __shared__ __align__(16) unsigned short Vt[2][DD * 72];   // 2 x 9 KB
  __shared__ __align__(16) unsigned short Sl[4][16 * 40];   // 5 KB
  const int blk = blockIdx.x;
  const int t = threadIdx.x;
  const int gc0 = blk * 2;   // global chunk ids gc0, gc0+1 (gc = bh*32+c)
  const int wr = t >> 6, l = t & 63, lg = l >> 4, lc = l & 15;

  // ---------------- phase 1: stage both chunks, compute partials ----------------
#pragma unroll
  for (int cc = 0; cc < 2; ++cc) {
    const size_t base = (size_t)(gc0 + cc) * (CH * DD);
    const float4* k4 = (const float4*)(kg + base);
    const float4* v4 = (const float4*)(vg + base);
#pragma unroll
    for (int r = 0; r < 4; ++r) {
      int idx4 = t + 256 * r;
      int j = idx4 >> 4, e0 = (idx4 & 15) << 2;
      float4 kk = k4[idx4];
      float ke[4];
      ke[0] = exp2f(kk.x * C1) + EPSF;
      ke[1] = exp2f(kk.y * C1) + EPSF;
      ke[2] = exp2f(kk.z * C1) + EPSF;
      ke[3] = exp2f(kk.w * C1) + EPSF;
      short4 w;
      w.x = (short)f2bf(ke[0]); w.y = (short)f2bf(ke[1]);
      w.z = (short)f2bf(ke[2]); w.w = (short)f2bf(ke[3]);
      *(short4*)&Kb[cc][j * 72 + e0] = w;
      float4 vv = v4[idx4];
      float vv0[4] = {vv.x, vv.y, vv.z, vv.w};
#pragma unroll
      for (int i = 0; i < 4; ++i) {
        Kt[cc][(e0 + i) * 72 + j] = f2bf(ke[i]);
        Vt[cc][(e0 + i) * 72 + j] = f2bf(vv0[i]);
      }
    }
  }
  __syncthreads();
#pragma unroll
  for (int cc = 0; cc < 2; ++cc) {
    const int gc = gc0 + cc;
    // A fragments: rows e = wr*16+lc, k = j
    bf16x8 a0 = *(const bf16x8*)&Kt[cc][(wr * 16 + lc) * 72 + lg * 8];
    bf16x8 a1 = *(const bf16x8*)&Kt[cc][(wr * 16 + lc) * 72 + 32 + lg * 8];
    float ks = 0.f;
#pragma unroll
    for (int i = 0; i < 8; ++i) ks += bf2f((unsigned short)a0[i]) + bf2f((unsigned short)a1[i]);
    ks += __shfl_xor(ks, 16, 64);
    ks += __shfl_xor(ks, 32, 64);
    if (lg == 0) ksum[(size_t)gc * DD + wr * 16 + lc] = ks;
    f32x4 acc[4];
#pragma unroll
    for (int ft = 0; ft < 4; ++ft) acc[ft] = (f32x4){0.f, 0.f, 0.f, 0.f};
#pragma unroll
    for (int ft = 0; ft < 4; ++ft) {
      bf16x8 b0 = *(const bf16x8*)&Vt[cc][(ft * 16 + lc) * 72 + lg * 8];
      bf16x8 b1 = *(const bf16x8*)&Vt[cc][(ft * 16 + lc) * 72 + 32 + lg * 8];
      acc[ft] = __builtin_amdgcn_mfma_f32_16x16x32_bf16(a0, b0, acc[ft], 0, 0, 0);
      acc[ft] = __builtin_amdgcn_mfma_f32_16x16x32_bf16(a1, b1, acc[ft], 0, 0, 0);
    }
    // store ws[gc][f][e] bf16; rows e = wr*16 + lg*4 + reg
    unsigned short* kvb = kvws + (size_t)gc * (DD * DD);
    const int e0 = wr * 16 + lg * 4;
#pragma unroll
    for (int ft = 0; ft < 4; ++ft) {
      short4 w;
      w.x = (short)f2bf(acc[ft][0]);
      w.y = (short)f2bf(acc[ft][1]);
      w.z = (short)f2bf(acc[ft][2]);
      w.w = (short)f2bf(acc[ft][3]);
      *(short4*)&kvb[(ft * 16 + lc) * DD + e0] = w;
    }
  }

  __threadfence();
  cg::this_grid().sync();

  // ---------------- phase 2: exclusive prefix scan over chunks ----------------
  {
    const int tid = blk * 256 + t;   // 0..131071
    if (tid < BHN * 2048) {          // kv dword-columns: 32 bh x 2048
      const int bh = tid >> 11, col = tid & 2047;
      unsigned* p = (unsigned*)kvws + (size_t)bh * NC * 2048 + col;
      unsigned x[NC];
#pragma unroll
      for (int c = 0; c < NC; ++c) x[c] = p[(size_t)c * 2048];
      float a0 = 0.f, a1 = 0.f;
#pragma unroll
      for (int c = 0; c < NC; ++c) {
        float x0 = bf2f((unsigned short)(x[c] & 0xffffu));
        float x1 = bf2f((unsigned short)(x[c] >> 16));
        p[(size_t)c * 2048] = (unsigned)f2bf(a0) | ((unsigned)f2bf(a1) << 16);
        a0 += x0; a1 += x1;
      }
    } else if (tid < BHN * 2048 + BHN * DD) {   // ksum columns: 32 bh x 64
      const int gid = tid - BHN * 2048;
      const int bh = gid >> 6, e = gid & 63;
      float* pk = ksum + (size_t)bh * NC * DD + e;
      float x[NC];
#pragma unroll
      for (int c = 0; c < NC; ++c) x[c] = pk[(size_t)c * DD];
      float run = 0.f;
#pragma unroll
      for (int c = 0; c < NC; ++c) { pk[(size_t)c * DD] = run; run += x[c]; }
    }
  }

  __threadfence();
  cg::this_grid().sync();

  // ---------------- phase 3: output (K'/V' still resident in LDS) ----------------
#pragma unroll
  for (int cc = 0; cc < 2; ++cc) {
    const int gc = gc0 + cc;
    const size_t base = (size_t)gc * (CH * DD);
    // Q': row = wr*16+lc, cols kt*32 + lg*8 .. +7
    float qe[2][8];
    const float* qrow = qg + base + (size_t)(wr * 16 + lc) * DD;
#pragma unroll
    for (int kt = 0; kt < 2; ++kt) {
      float4 x = *(const float4*)(qrow + kt * 32 + lg * 8);
      float4 y = *(const float4*)(qrow + kt * 32 + lg * 8 + 4);
      qe[kt][0] = x.x; qe[kt][1] = x.y; qe[kt][2] = x.z; qe[kt][3] = x.w;
      qe[kt][4] = y.x; qe[kt][5] = y.y; qe[kt][6] = y.z; qe[kt][7] = y.w;
    }
    bf16x8 qf[2];
    float dp = 0.f;
    const float* ksp = ksum + (size_t)gc * DD;
#pragma unroll
    for (int kt = 0; kt < 2; ++kt) {
      float4 s0 = *(const float4*)(ksp + kt * 32 + lg * 8);
      float4 s1 = *(const float4*)(ksp + kt * 32 + lg * 8 + 4);
      float ksv[8] = {s0.x, s0.y, s0.z, s0.w, s1.x, s1.y, s1.z, s1.w};
#pragma unroll
      for (int i = 0; i < 8; ++i) {
        float qv = exp2f(qe[kt][i] * C1) + EPSF;
        dp += qv * (ksv[i] + EPSF);
        qf[kt][i] = (short)f2bf(qv);
      }
    }
    dp += __shfl_xor(dp, 16, 64);
    dp += __shfl_xor(dp, 32, 64);   // full-row q'.(ksum_excl+EPS)

    f32x4 o[4];
#pragma unroll
    for (int ft = 0; ft < 4; ++ft) o[ft] = (f32x4){0.f, 0.f, 0.f, 0.f};

    // O_pref: B fragments direct from ws [gc][f][e] (L2/L3-resident)
    const unsigned short* kvb = kvws + (size_t)gc * (DD * DD);
#pragma unroll
    for (int kt = 0; kt < 2; ++kt) {
#pragma unroll
      for (int ft = 0; ft < 4; ++ft) {
        bf16x8 b = *(const bf16x8*)(kvb + (ft * 16 + lc) * DD + kt * 32 + lg * 8);
        o[ft] = __builtin_amdgcn_mfma_f32_16x16x32_bf16(qf[kt], b, o[ft], 0, 0, 0);
      }
    }

    // causal intra part
    float rs0 = 0.f, rs1 = 0.f, rs2 = 0.f, rs3 = 0.f;
    const int irow = wr * 16 + lg * 4;   // + reg
    const int ng = (wr >> 1) + 1;
    for (int g = 0; g < ng; ++g) {
#pragma unroll
      for (int c2 = 0; c2 < 2; ++c2) {
        const int ct = 2 * g + c2;
        bf16x8 kb0 = *(const bf16x8*)&Kb[cc][(ct * 16 + lc) * 72 + lg * 8];
        bf16x8 kb1 = *(const bf16x8*)&Kb[cc][(ct * 16 + lc) * 72 + 32 + lg * 8];
        f32x4 s = (f32x4){0.f, 0.f, 0.f, 0.f};
        s = __builtin_amdgcn_mfma_f32_16x16x32_bf16(qf[0], kb0, s, 0, 0, 0);
        s = __builtin_amdgcn_mfma_f32_16x16x32_bf16(qf[1], kb1, s, 0, 0, 0);
        const int j = ct * 16 + lc;
        float v0 = (j <= irow + 0) ? s[0] : 0.f;
        float v1 = (j <= irow + 1) ? s[1] : 0.f;
        float v2 = (j <= irow + 2) ? s[2] : 0.f;
        float v3 = (j <= irow + 3) ? s[3] : 0.f;
        rs0 += v0; rs1 += v1; rs2 += v2; rs3 += v3;
        unsigned short* sl = &Sl[wr][0];
        sl[(lg * 4 + 0) * 40 + c2 * 16 + lc] = f2bf(v0);
        sl[(lg * 4 + 1) * 40 + c2 * 16 + lc] = f2bf(v1);
        sl[(lg * 4 + 2) * 40 + c2 * 16 + lc] = f2bf(v2);
        sl[(lg * 4 + 3) * 40 + c2 * 16 + lc] = f2bf(v3);
      }
      // A fragment of masked S (wave-local; DS pipe in-order within a wave)
      bf16x8 sa = *(const bf16x8*)&Sl[wr][lc * 40 + lg * 8];
#pragma unroll
      for (int ft = 0; ft < 4; ++ft) {
        bf16x8 vb = *(const bf16x8*)&Vt[cc][(ft * 16 + lc) * 72 + g * 32 + lg * 8];
        o[ft] = __builtin_amdgcn_mfma_f32_16x16x32_bf16(sa, vb, o[ft], 0, 0, 0);
      }
    }
#pragma unroll
    for (int m = 1; m < 16; m <<= 1) {
      rs0 += __shfl_xor(rs0, m, 64);
      rs1 += __shfl_xor(rs1, m, 64);
      rs2 += __shfl_xor(rs2, m, 64);
      rs3 += __shfl_xor(rs3, m, 64);
    }
    float rsv[4] = {rs0, rs1, rs2, rs3};
    float* op = out + base;
#pragma unroll
    for (int reg = 0; reg < 4; ++reg) {
      float d = __shfl(dp, lg * 4 + reg, 64) + rsv[reg];
      float dinv = 1.0f / d;
#pragma unroll
      for (int ft = 0; ft < 4; ++ft) {
        op[(size_t)(irow + reg) * DD + ft * 16 + lc] = o[ft][reg] * dinv;
      }
    }
  }
}

extern "C" void kernel_launch(void* const* d_in, const int* in_sizes, int n_in,
                              void* d_out, int out_size, void* d_ws, size_t ws_size,
                              hipStream_t stream) {
  const float* q = (const float*)d_in[0];
  const float* k = (const float*)d_in[1];
  const float* v = (const float*)d_in[2];
  float* out = (float*)d_out;
  // ws layout: ksum[1024*64] f32 | kv bf16 [1024*4096]
  float* ksum = (float*)d_ws;
  unsigned short* kvws = (unsigned short*)(ksum + (size_t)NCHUNK * DD);

  void* args[] = {(void*)&q, (void*)&k, (void*)&v,
                  (void*)&ksum, (void*)&kvws, (void*)&out};
  hipLaunchCooperativeKernel((const void*)perf_fused, dim3(NCHUNK / 2), dim3(256),
                             args, 0, stream);
}

// Round 6
// 116.842 us; speedup vs baseline: 2.9147x; 2.9147x over previous
//
#include <hip/hip_runtime.h>

// Performer exp-kernel linear causal attention — 2-kernel, no grid sync.
// B=4 H=8 N=2048 D=64 fp32. Maxes cancel in the ratio (verified R4).
// A: per-chunk KV^T partial (bf16) + Ksum        (1024 blocks, MFMA)
// B: per-chunk output; block redundantly sums the j<c partials (L2-resident,
//    ~500 adds/thread worst case) -> no scan kernel, no cross-block dependency.
// R5 lesson: cg grid.sync() costs ~100us on gfx950 — never again.

#define NSEQ 2048
#define DD 64
#define CH 64
#define NC (NSEQ / CH)   // 32
#define BHN 32
#define NCHUNK (BHN * NC)   // 1024
#define EPSF 1e-8f
#define NRM 0.35355339059327373f   // 64^(-0.25)
#define C1 (NRM * 1.4426950408889634f)   // nrm * log2(e)

typedef short bf16x8 __attribute__((ext_vector_type(8)));
typedef float f32x4 __attribute__((ext_vector_type(4)));

__device__ __forceinline__ unsigned short f2bf(float f) {
  union { float f; unsigned u; } c; c.f = f;
  unsigned u = c.u + 0x7fffu + ((c.u >> 16) & 1u);
  return (unsigned short)(u >> 16);
}
__device__ __forceinline__ float bf2f(unsigned short s) {
  union { unsigned u; float f; } c; c.u = ((unsigned)s) << 16;
  return c.f;
}

// ---------------- A: per-chunk KV partial (bf16) + Ksum ----------------
__global__ __launch_bounds__(256) void kA_partial(const float* __restrict__ kg,
                                                  const float* __restrict__ vg,
                                                  float* __restrict__ ksum,
                                                  unsigned short* __restrict__ kvws) {
  __shared__ __align__(16) unsigned short Kt[DD * 72];   // K'^T  [e][j]
  __shared__ __align__(16) unsigned short Vt[DD * 72];   // V^T   [f][j]
  const int blk = blockIdx.x;
  const int t = threadIdx.x;
  const size_t base = (size_t)blk * (CH * DD);
  const float4* k4 = (const float4*)(kg + base);
  const float4* v4 = (const float4*)(vg + base);
#pragma unroll
  for (int r = 0; r < 4; ++r) {
    int idx4 = t + 256 * r;
    int j = idx4 >> 4, e0 = (idx4 & 15) << 2;
    float4 kk = k4[idx4];
    float kv0[4] = {kk.x, kk.y, kk.z, kk.w};
    float4 vv = v4[idx4];
    float vv0[4] = {vv.x, vv.y, vv.z, vv.w};
#pragma unroll
    for (int i = 0; i < 4; ++i) {
      Kt[(e0 + i) * 72 + j] = f2bf(exp2f(kv0[i] * C1) + EPSF);
      Vt[(e0 + i) * 72 + j] = f2bf(vv0[i]);
    }
  }
  __syncthreads();
  const int wr = t >> 6, l = t & 63, lg = l >> 4, lc = l & 15;
  // A fragments: rows e = wr*16+lc, k = j
  bf16x8 a0 = *(const bf16x8*)&Kt[(wr * 16 + lc) * 72 + lg * 8];
  bf16x8 a1 = *(const bf16x8*)&Kt[(wr * 16 + lc) * 72 + 32 + lg * 8];
  // Ksum over j of K'[j][e]
  float ks = 0.f;
#pragma unroll
  for (int i = 0; i < 8; ++i) ks += bf2f((unsigned short)a0[i]) + bf2f((unsigned short)a1[i]);
  ks += __shfl_xor(ks, 16, 64);
  ks += __shfl_xor(ks, 32, 64);
  if (lg == 0) ksum[(size_t)blk * DD + wr * 16 + lc] = ks;
  // KV = K'^T @ V
  f32x4 acc[4];
#pragma unroll
  for (int ft = 0; ft < 4; ++ft) acc[ft] = (f32x4){0.f, 0.f, 0.f, 0.f};
#pragma unroll
  for (int ft = 0; ft < 4; ++ft) {
    bf16x8 b0 = *(const bf16x8*)&Vt[(ft * 16 + lc) * 72 + lg * 8];
    bf16x8 b1 = *(const bf16x8*)&Vt[(ft * 16 + lc) * 72 + 32 + lg * 8];
    acc[ft] = __builtin_amdgcn_mfma_f32_16x16x32_bf16(a0, b0, acc[ft], 0, 0, 0);
    acc[ft] = __builtin_amdgcn_mfma_f32_16x16x32_bf16(a1, b1, acc[ft], 0, 0, 0);
  }
  // store ws[blk][f][e] bf16; rows e = wr*16 + lg*4 + reg
  unsigned short* kvb = kvws + (size_t)blk * (DD * DD);
  const int e0 = wr * 16 + lg * 4;
#pragma unroll
  for (int ft = 0; ft < 4; ++ft) {
    short4 w;
    w.x = (short)f2bf(acc[ft][0]);
    w.y = (short)f2bf(acc[ft][1]);
    w.z = (short)f2bf(acc[ft][2]);
    w.w = (short)f2bf(acc[ft][3]);
    *(short4*)&kvb[(ft * 16 + lc) * DD + e0] = w;
  }
}

// ---------------- B: prefix-accumulate + output ----------------
__global__ __launch_bounds__(256) void kB_out(const float* __restrict__ qg,
                                              const float* __restrict__ kg,
                                              const float* __restrict__ vg,
                                              const float* __restrict__ ksum,
                                              const unsigned short* __restrict__ kvws,
                                              float* __restrict__ out) {
  __shared__ __align__(16) unsigned short Kb[CH * 72];      // K' row-major [j][e]
  __shared__ __align__(16) unsigned short Vt[DD * 72];      // V^T [f][j]
  __shared__ __align__(16) unsigned short KVp[DD * 72];     // prefix KV [f][e] bf16
  __shared__ __align__(16) unsigned short Sl[4][16 * 40];   // per-wave masked S
  __shared__ float kspf[DD];                                // prefix ksum
  const int blk = blockIdx.x;
  const int bh = blk >> 5, c = blk & 31;
  const int t = threadIdx.x;
  const size_t base = (size_t)blk * (CH * DD);
  const float4* k4 = (const float4*)(kg + base);
  const float4* v4 = (const float4*)(vg + base);
  // stage K' (row-major) and V^T
#pragma unroll
  for (int r = 0; r < 4; ++r) {
    int idx4 = t + 256 * r;
    int j = idx4 >> 4, e0 = (idx4 & 15) << 2;
    float4 kk = k4[idx4];
    short4 w;
    w.x = (short)f2bf(exp2f(kk.x * C1) + EPSF);
    w.y = (short)f2bf(exp2f(kk.y * C1) + EPSF);
    w.z = (short)f2bf(exp2f(kk.z * C1) + EPSF);
    w.w = (short)f2bf(exp2f(kk.w * C1) + EPSF);
    *(short4*)&Kb[j * 72 + e0] = w;
    float4 vv = v4[idx4];
    float vv0[4] = {vv.x, vv.y, vv.z, vv.w};
#pragma unroll
    for (int i = 0; i < 4; ++i) Vt[(e0 + i) * 72 + j] = f2bf(vv0[i]);
  }
  // redundant prefix accumulation over j<c partials (L2/L3-resident ws).
  // thread t owns 16 elems of [f][e]: f = t>>2, e0 = (t&3)*16.
  {
    float pf[16];
#pragma unroll
    for (int i = 0; i < 16; ++i) pf[i] = 0.f;
    const unsigned short* kvbase =
        kvws + ((size_t)bh * NC) * (DD * DD) + (size_t)t * 16;
    for (int j = 0; j < c; ++j) {
      bf16x8 x0 = *(const bf16x8*)(kvbase + (size_t)j * (DD * DD));
      bf16x8 x1 = *(const bf16x8*)(kvbase + (size_t)j * (DD * DD) + 8);
#pragma unroll
      for (int i = 0; i < 8; ++i) {
        pf[i]     += bf2f((unsigned short)x0[i]);
        pf[8 + i] += bf2f((unsigned short)x1[i]);
      }
    }
    bf16x8 w0, w1;
#pragma unroll
    for (int i = 0; i < 8; ++i) {
      w0[i] = (short)f2bf(pf[i]);
      w1[i] = (short)f2bf(pf[8 + i]);
    }
    unsigned short* kvrow = &KVp[(t >> 2) * 72 + (t & 3) * 16];
    *(bf16x8*)kvrow = w0;
    *(bf16x8*)(kvrow + 8) = w1;
  }
  if (t < DD) {
    float s = 0.f;
    const float* kp = ksum + ((size_t)bh * NC) * DD + t;
    for (int j = 0; j < c; ++j) s += kp[(size_t)j * DD];
    kspf[t] = s;
  }
  const int wr = t >> 6, l = t & 63, lg = l >> 4, lc = l & 15;
  // Q': row = wr*16+lc, cols kt*32 + lg*8 .. +7
  float qe[2][8];
  const float* qrow = qg + base + (size_t)(wr * 16 + lc) * DD;
#pragma unroll
  for (int kt = 0; kt < 2; ++kt) {
    float4 x = *(const float4*)(qrow + kt * 32 + lg * 8);
    float4 y = *(const float4*)(qrow + kt * 32 + lg * 8 + 4);
    qe[kt][0] = x.x; qe[kt][1] = x.y; qe[kt][2] = x.z; qe[kt][3] = x.w;
    qe[kt][4] = y.x; qe[kt][5] = y.y; qe[kt][6] = y.z; qe[kt][7] = y.w;
  }
  __syncthreads();

  bf16x8 qf[2];
  float dp = 0.f;
#pragma unroll
  for (int kt = 0; kt < 2; ++kt) {
    float4 s0 = *(const float4*)(kspf + kt * 32 + lg * 8);
    float4 s1 = *(const float4*)(kspf + kt * 32 + lg * 8 + 4);
    float ksv[8] = {s0.x, s0.y, s0.z, s0.w, s1.x, s1.y, s1.z, s1.w};
#pragma unroll
    for (int i = 0; i < 8; ++i) {
      float qv = exp2f(qe[kt][i] * C1) + EPSF;
      dp += qv * (ksv[i] + EPSF);
      qf[kt][i] = (short)f2bf(qv);
    }
  }
  dp += __shfl_xor(dp, 16, 64);
  dp += __shfl_xor(dp, 32, 64);   // full-row q'.(ksum_excl+EPS)

  f32x4 o[4];
#pragma unroll
  for (int ft = 0; ft < 4; ++ft) o[ft] = (f32x4){0.f, 0.f, 0.f, 0.f};

  // O_pref: B fragments from LDS KVp [f][e]
#pragma unroll
  for (int kt = 0; kt < 2; ++kt) {
#pragma unroll
    for (int ft = 0; ft < 4; ++ft) {
      bf16x8 b = *(const bf16x8*)&KVp[(ft * 16 + lc) * 72 + kt * 32 + lg * 8];
      o[ft] = __builtin_amdgcn_mfma_f32_16x16x32_bf16(qf[kt], b, o[ft], 0, 0, 0);
    }
  }

  // causal intra part
  float rs0 = 0.f, rs1 = 0.f, rs2 = 0.f, rs3 = 0.f;
  const int irow = wr * 16 + lg * 4;   // + reg
  const int ng = (wr >> 1) + 1;
  for (int g = 0; g < ng; ++g) {
#pragma unroll
    for (int c2 = 0; c2 < 2; ++c2) {
      const int ct = 2 * g + c2;
      bf16x8 kb0 = *(const bf16x8*)&Kb[(ct * 16 + lc) * 72 + lg * 8];
      bf16x8 kb1 = *(const bf16x8*)&Kb[(ct * 16 + lc) * 72 + 32 + lg * 8];
      f32x4 s = (f32x4){0.f, 0.f, 0.f, 0.f};
      s = __builtin_amdgcn_mfma_f32_16x16x32_bf16(qf[0], kb0, s, 0, 0, 0);
      s = __builtin_amdgcn_mfma_f32_16x16x32_bf16(qf[1], kb1, s, 0, 0, 0);
      const int j = ct * 16 + lc;
      float v0 = (j <= irow + 0) ? s[0] : 0.f;
      float v1 = (j <= irow + 1) ? s[1] : 0.f;
      float v2 = (j <= irow + 2) ? s[2] : 0.f;
      float v3 = (j <= irow + 3) ? s[3] : 0.f;
      rs0 += v0; rs1 += v1; rs2 += v2; rs3 += v3;
      unsigned short* sl = &Sl[wr][0];
      sl[(lg * 4 + 0) * 40 + c2 * 16 + lc] = f2bf(v0);
      sl[(lg * 4 + 1) * 40 + c2 * 16 + lc] = f2bf(v1);
      sl[(lg * 4 + 2) * 40 + c2 * 16 + lc] = f2bf(v2);
      sl[(lg * 4 + 3) * 40 + c2 * 16 + lc] = f2bf(v3);
    }
    // A fragment of masked S (wave-local; DS pipe in-order within a wave)
    bf16x8 sa = *(const bf16x8*)&Sl[wr][lc * 40 + lg * 8];
#pragma unroll
    for (int ft = 0; ft < 4; ++ft) {
      bf16x8 vb = *(const bf16x8*)&Vt[(ft * 16 + lc) * 72 + g * 32 + lg * 8];
      o[ft] = __builtin_amdgcn_mfma_f32_16x16x32_bf16(sa, vb, o[ft], 0, 0, 0);
    }
  }
#pragma unroll
  for (int m = 1; m < 16; m <<= 1) {
    rs0 += __shfl_xor(rs0, m, 64);
    rs1 += __shfl_xor(rs1, m, 64);
    rs2 += __shfl_xor(rs2, m, 64);
    rs3 += __shfl_xor(rs3, m, 64);
  }
  float rsv[4] = {rs0, rs1, rs2, rs3};
  float* op = out + base;
#pragma unroll
  for (int reg = 0; reg < 4; ++reg) {
    float d = __shfl(dp, lg * 4 + reg, 64) + rsv[reg];
    float dinv = 1.0f / d;
#pragma unroll
    for (int ft = 0; ft < 4; ++ft) {
      op[(size_t)(irow + reg) * DD + ft * 16 + lc] = o[ft][reg] * dinv;
    }
  }
}

extern "C" void kernel_launch(void* const* d_in, const int* in_sizes, int n_in,
                              void* d_out, int out_size, void* d_ws, size_t ws_size,
                              hipStream_t stream) {
  const float* q = (const float*)d_in[0];
  const float* k = (const float*)d_in[1];
  const float* v = (const float*)d_in[2];
  float* out = (float*)d_out;
  // ws layout: ksum[1024*64] f32 | kv bf16 [1024*4096]
  float* ksum = (float*)d_ws;
  unsigned short* kvws = (unsigned short*)(ksum + (size_t)NCHUNK * DD);

  hipLaunchKernelGGL(kA_partial, dim3(NCHUNK), dim3(256), 0, stream,
                     k, v, ksum, kvws);
  hipLaunchKernelGGL(kB_out, dim3(NCHUNK), dim3(256), 0, stream,
                     q, k, v, ksum, kvws, out);
}

// Round 8
// 112.810 us; speedup vs baseline: 3.0188x; 1.0357x over previous
//
#include <hip/hip_runtime.h>

// Performer exp-kernel linear causal attention — 2-kernel, no grid sync.
// B=4 H=8 N=2048 D=64 fp32. Maxes cancel in the ratio (verified R4).
// A: per-chunk KV^T partial (bf16) + Ksum        (1024 blocks, MFMA)
// B: per-chunk output; block redundantly sums the j<c partials (L2-resident)
// R5 lesson: cg grid.sync() ~100us on gfx950 — never.
// R8: staging = one-pass 4x4 register transpose (thread t: j0=4*(t>>4),
//     e4=t&15) -> packed b64 LDS writes. R7's OOB bug (double-counted rows)
//     fixed. Prefix-accum batched 8-wide masked loads (L2 pipelining).

#define NSEQ 2048
#define DD 64
#define CH 64
#define NC (NSEQ / CH)   // 32
#define BHN 32
#define NCHUNK (BHN * NC)   // 1024
#define EPSF 1e-8f
#define NRM 0.35355339059327373f   // 64^(-0.25)
#define C1 (NRM * 1.4426950408889634f)   // nrm * log2(e)

typedef short bf16x8 __attribute__((ext_vector_type(8)));
typedef float f32x4 __attribute__((ext_vector_type(4)));

__device__ __forceinline__ unsigned short f2bf(float f) {
  union { float f; unsigned u; } c; c.f = f;
  unsigned u = c.u + 0x7fffu + ((c.u >> 16) & 1u);
  return (unsigned short)(u >> 16);
}
__device__ __forceinline__ float bf2f(unsigned short s) {
  union { unsigned u; float f; } c; c.u = ((unsigned)s) << 16;
  return c.f;
}

// ---------------- A: per-chunk KV partial (bf16) + Ksum ----------------
__global__ __launch_bounds__(256) void kA_partial(const float* __restrict__ kg,
                                                  const float* __restrict__ vg,
                                                  float* __restrict__ ksum,
                                                  unsigned short* __restrict__ kvws) {
  __shared__ __align__(16) unsigned short Kt[DD * 72];   // K'^T  [e][j]
  __shared__ __align__(16) unsigned short Vt[DD * 72];   // V^T   [f][j]
  const int blk = blockIdx.x;
  const int t = threadIdx.x;
  const size_t base = (size_t)blk * (CH * DD);
  const float4* k4 = (const float4*)(kg + base);
  const float4* v4 = (const float4*)(vg + base);
  // one-pass 4x4 tile: rows j0..j0+3, cols e0..e0+3
  {
    const int j0 = (t >> 4) << 2;   // 0..60
    const int e4 = t & 15, e0 = e4 << 2;
    float ka[4][4], va[4][4];
#pragma unroll
    for (int jj = 0; jj < 4; ++jj) {
      float4 kk = k4[(j0 + jj) * 16 + e4];
      float4 vv = v4[(j0 + jj) * 16 + e4];
      ka[jj][0] = exp2f(kk.x * C1) + EPSF;
      ka[jj][1] = exp2f(kk.y * C1) + EPSF;
      ka[jj][2] = exp2f(kk.z * C1) + EPSF;
      ka[jj][3] = exp2f(kk.w * C1) + EPSF;
      va[jj][0] = vv.x; va[jj][1] = vv.y; va[jj][2] = vv.z; va[jj][3] = vv.w;
    }
#pragma unroll
    for (int i = 0; i < 4; ++i) {
      short4 wk, wv;
      wk.x = (short)f2bf(ka[0][i]); wk.y = (short)f2bf(ka[1][i]);
      wk.z = (short)f2bf(ka[2][i]); wk.w = (short)f2bf(ka[3][i]);
      wv.x = (short)f2bf(va[0][i]); wv.y = (short)f2bf(va[1][i]);
      wv.z = (short)f2bf(va[2][i]); wv.w = (short)f2bf(va[3][i]);
      *(short4*)&Kt[(e0 + i) * 72 + j0] = wk;
      *(short4*)&Vt[(e0 + i) * 72 + j0] = wv;
    }
  }
  __syncthreads();
  const int wr = t >> 6, l = t & 63, lg = l >> 4, lc = l & 15;
  // A fragments: rows e = wr*16+lc, k = j
  bf16x8 a0 = *(const bf16x8*)&Kt[(wr * 16 + lc) * 72 + lg * 8];
  bf16x8 a1 = *(const bf16x8*)&Kt[(wr * 16 + lc) * 72 + 32 + lg * 8];
  // Ksum over j of K'[j][e]
  float ks = 0.f;
#pragma unroll
  for (int i = 0; i < 8; ++i) ks += bf2f((unsigned short)a0[i]) + bf2f((unsigned short)a1[i]);
  ks += __shfl_xor(ks, 16, 64);
  ks += __shfl_xor(ks, 32, 64);
  if (lg == 0) ksum[(size_t)blk * DD + wr * 16 + lc] = ks;
  // KV = K'^T @ V
  f32x4 acc[4];
#pragma unroll
  for (int ft = 0; ft < 4; ++ft) acc[ft] = (f32x4){0.f, 0.f, 0.f, 0.f};
#pragma unroll
  for (int ft = 0; ft < 4; ++ft) {
    bf16x8 b0 = *(const bf16x8*)&Vt[(ft * 16 + lc) * 72 + lg * 8];
    bf16x8 b1 = *(const bf16x8*)&Vt[(ft * 16 + lc) * 72 + 32 + lg * 8];
    acc[ft] = __builtin_amdgcn_mfma_f32_16x16x32_bf16(a0, b0, acc[ft], 0, 0, 0);
    acc[ft] = __builtin_amdgcn_mfma_f32_16x16x32_bf16(a1, b1, acc[ft], 0, 0, 0);
  }
  // store ws[blk][f][e] bf16; rows e = wr*16 + lg*4 + reg
  unsigned short* kvb = kvws + (size_t)blk * (DD * DD);
  const int ee0 = wr * 16 + lg * 4;
#pragma unroll
  for (int ft = 0; ft < 4; ++ft) {
    short4 w;
    w.x = (short)f2bf(acc[ft][0]);
    w.y = (short)f2bf(acc[ft][1]);
    w.z = (short)f2bf(acc[ft][2]);
    w.w = (short)f2bf(acc[ft][3]);
    *(short4*)&kvb[(ft * 16 + lc) * DD + ee0] = w;
  }
}

// ---------------- B: prefix-accumulate + output ----------------
__global__ __launch_bounds__(256) void kB_out(const float* __restrict__ qg,
                                              const float* __restrict__ kg,
                                              const float* __restrict__ vg,
                                              const float* __restrict__ ksum,
                                              const unsigned short* __restrict__ kvws,
                                              float* __restrict__ out) {
  __shared__ __align__(16) unsigned short Kb[CH * 72];      // K' row-major [j][e]
  __shared__ __align__(16) unsigned short Vt[DD * 72];      // V^T [f][j]
  __shared__ __align__(16) unsigned short KVp[DD * 72];     // prefix KV [f][e] bf16
  __shared__ __align__(16) unsigned short Sl[4][16 * 40];   // per-wave masked S
  __shared__ float kspf[DD];                                // prefix ksum
  const int blk = blockIdx.x;
  const int bh = blk >> 5, c = blk & 31;
  const int t = threadIdx.x;
  const size_t base = (size_t)blk * (CH * DD);
  const float4* k4 = (const float4*)(kg + base);
  const float4* v4 = (const float4*)(vg + base);
  // stage K' (row-major, b64 writes) and V^T (register 4x4 transpose, b64)
  {
    const int j0 = (t >> 4) << 2;   // 0..60
    const int e4 = t & 15, e0 = e4 << 2;
    float va[4][4];
#pragma unroll
    for (int jj = 0; jj < 4; ++jj) {
      float4 kk = k4[(j0 + jj) * 16 + e4];
      float4 vv = v4[(j0 + jj) * 16 + e4];
      short4 w;
      w.x = (short)f2bf(exp2f(kk.x * C1) + EPSF);
      w.y = (short)f2bf(exp2f(kk.y * C1) + EPSF);
      w.z = (short)f2bf(exp2f(kk.z * C1) + EPSF);
      w.w = (short)f2bf(exp2f(kk.w * C1) + EPSF);
      *(short4*)&Kb[(j0 + jj) * 72 + e0] = w;
      va[jj][0] = vv.x; va[jj][1] = vv.y; va[jj][2] = vv.z; va[jj][3] = vv.w;
    }
#pragma unroll
    for (int i = 0; i < 4; ++i) {
      short4 wv;
      wv.x = (short)f2bf(va[0][i]); wv.y = (short)f2bf(va[1][i]);
      wv.z = (short)f2bf(va[2][i]); wv.w = (short)f2bf(va[3][i]);
      *(short4*)&Vt[(e0 + i) * 72 + j0] = wv;
    }
  }
  // redundant prefix accumulation over j<c partials (L2/L3-resident ws).
  // thread t owns 16 elems of [f][e]; batches of 8 unconditional loads,
  // masked accumulate (ascending j -> bitwise-identical to serial sum).
  {
    float pf[16];
#pragma unroll
    for (int i = 0; i < 16; ++i) pf[i] = 0.f;
    const unsigned short* kvbase =
        kvws + ((size_t)bh * NC) * (DD * DD) + (size_t)t * 16;
#pragma unroll
    for (int j0 = 0; j0 < NC; j0 += 8) {
      if (j0 >= c) break;   // wave-uniform
      bf16x8 x0[8], x1[8];
#pragma unroll
      for (int jj = 0; jj < 8; ++jj) {
        const unsigned short* p = kvbase + (size_t)(j0 + jj) * (DD * DD);
        x0[jj] = *(const bf16x8*)p;
        x1[jj] = *(const bf16x8*)(p + 8);
      }
#pragma unroll
      for (int jj = 0; jj < 8; ++jj) {
        float w = (j0 + jj < c) ? 1.f : 0.f;
#pragma unroll
        for (int i = 0; i < 8; ++i) {
          pf[i]     += w * bf2f((unsigned short)x0[jj][i]);
          pf[8 + i] += w * bf2f((unsigned short)x1[jj][i]);
        }
      }
    }
    bf16x8 w0, w1;
#pragma unroll
    for (int i = 0; i < 8; ++i) {
      w0[i] = (short)f2bf(pf[i]);
      w1[i] = (short)f2bf(pf[8 + i]);
    }
    unsigned short* kvrow = &KVp[(t >> 2) * 72 + (t & 3) * 16];
    *(bf16x8*)kvrow = w0;
    *(bf16x8*)(kvrow + 8) = w1;
  }
  if (t < DD) {
    float s = 0.f;
    const float* kp = ksum + ((size_t)bh * NC) * DD + t;
#pragma unroll
    for (int j = 0; j < NC - 1; ++j) {   // 31 pipelined loads, masked add
      float x = kp[(size_t)j * DD];
      s += (j < c) ? x : 0.f;
    }
    kspf[t] = s;
  }
  const int wr = t >> 6, l = t & 63, lg = l >> 4, lc = l & 15;
  // Q': row = wr*16+lc, cols kt*32 + lg*8 .. +7
  float qe[2][8];
  const float* qrow = qg + base + (size_t)(wr * 16 + lc) * DD;
#pragma unroll
  for (int kt = 0; kt < 2; ++kt) {
    float4 x = *(const float4*)(qrow + kt * 32 + lg * 8);
    float4 y = *(const float4*)(qrow + kt * 32 + lg * 8 + 4);
    qe[kt][0] = x.x; qe[kt][1] = x.y; qe[kt][2] = x.z; qe[kt][3] = x.w;
    qe[kt][4] = y.x; qe[kt][5] = y.y; qe[kt][6] = y.z; qe[kt][7] = y.w;
  }
  __syncthreads();

  bf16x8 qf[2];
  float dp = 0.f;
#pragma unroll
  for (int kt = 0; kt < 2; ++kt) {
    float4 s0 = *(const float4*)(kspf + kt * 32 + lg * 8);
    float4 s1 = *(const float4*)(kspf + kt * 32 + lg * 8 + 4);
    float ksv[8] = {s0.x, s0.y, s0.z, s0.w, s1.x, s1.y, s1.z, s1.w};
#pragma unroll
    for (int i = 0; i < 8; ++i) {
      float qv = exp2f(qe[kt][i] * C1) + EPSF;
      dp += qv * (ksv[i] + EPSF);
      qf[kt][i] = (short)f2bf(qv);
    }
  }
  dp += __shfl_xor(dp, 16, 64);
  dp += __shfl_xor(dp, 32, 64);   // full-row q'.(ksum_excl+EPS)

  f32x4 o[4];
#pragma unroll
  for (int ft = 0; ft < 4; ++ft) o[ft] = (f32x4){0.f, 0.f, 0.f, 0.f};

  // O_pref: B fragments from LDS KVp [f][e]
#pragma unroll
  for (int kt = 0; kt < 2; ++kt) {
#pragma unroll
    for (int ft = 0; ft < 4; ++ft) {
      bf16x8 b = *(const bf16x8*)&KVp[(ft * 16 + lc) * 72 + kt * 32 + lg * 8];
      o[ft] = __builtin_amdgcn_mfma_f32_16x16x32_bf16(qf[kt], b, o[ft], 0, 0, 0);
    }
  }

  // causal intra part
  float rs0 = 0.f, rs1 = 0.f, rs2 = 0.f, rs3 = 0.f;
  const int irow = wr * 16 + lg * 4;   // + reg
  const int ng = (wr >> 1) + 1;
  for (int g = 0; g < ng; ++g) {
#pragma unroll
    for (int c2 = 0; c2 < 2; ++c2) {
      const int ct = 2 * g + c2;
      bf16x8 kb0 = *(const bf16x8*)&Kb[(ct * 16 + lc) * 72 + lg * 8];
      bf16x8 kb1 = *(const bf16x8*)&Kb[(ct * 16 + lc) * 72 + 32 + lg * 8];
      f32x4 s = (f32x4){0.f, 0.f, 0.f, 0.f};
      s = __builtin_amdgcn_mfma_f32_16x16x32_bf16(qf[0], kb0, s, 0, 0, 0);
      s = __builtin_amdgcn_mfma_f32_16x16x32_bf16(qf[1], kb1, s, 0, 0, 0);
      const int j = ct * 16 + lc;
      float v0 = (j <= irow + 0) ? s[0] : 0.f;
      float v1 = (j <= irow + 1) ? s[1] : 0.f;
      float v2 = (j <= irow + 2) ? s[2] : 0.f;
      float v3 = (j <= irow + 3) ? s[3] : 0.f;
      rs0 += v0; rs1 += v1; rs2 += v2; rs3 += v3;
      unsigned short* sl = &Sl[wr][0];
      sl[(lg * 4 + 0) * 40 + c2 * 16 + lc] = f2bf(v0);
      sl[(lg * 4 + 1) * 40 + c2 * 16 + lc] = f2bf(v1);
      sl[(lg * 4 + 2) * 40 + c2 * 16 + lc] = f2bf(v2);
      sl[(lg * 4 + 3) * 40 + c2 * 16 + lc] = f2bf(v3);
    }
    // A fragment of masked S (wave-local; DS pipe in-order within a wave)
    bf16x8 sa = *(const bf16x8*)&Sl[wr][lc * 40 + lg * 8];
#pragma unroll
    for (int ft = 0; ft < 4; ++ft) {
      bf16x8 vb = *(const bf16x8*)&Vt[(ft * 16 + lc) * 72 + g * 32 + lg * 8];
      o[ft] = __builtin_amdgcn_mfma_f32_16x16x32_bf16(sa, vb, o[ft], 0, 0, 0);
    }
  }
#pragma unroll
  for (int m = 1; m < 16; m <<= 1) {
    rs0 += __shfl_xor(rs0, m, 64);
    rs1 += __shfl_xor(rs1, m, 64);
    rs2 += __shfl_xor(rs2, m, 64);
    rs3 += __shfl_xor(rs3, m, 64);
  }
  float rsv[4] = {rs0, rs1, rs2, rs3};
  float* op = out + base;
#pragma unroll
  for (int reg = 0; reg < 4; ++reg) {
    float d = __shfl(dp, lg * 4 + reg, 64) + rsv[reg];
    float dinv = 1.0f / d;
#pragma unroll
    for (int ft = 0; ft < 4; ++ft) {
      op[(size_t)(irow + reg) * DD + ft * 16 + lc] = o[ft][reg] * dinv;
    }
  }
}

extern "C" void kernel_launch(void* const* d_in, const int* in_sizes, int n_in,
                              void* d_out, int out_size, void* d_ws, size_t ws_size,
                              hipStream_t stream) {
  const float* q = (const float*)d_in[0];
  const float* k = (const float*)d_in[1];
  const float* v = (const float*)d_in[2];
  float* out = (float*)d_out;
  // ws layout: ksum[1024*64] f32 | kv bf16 [1024*4096]
  float* ksum = (float*)d_ws;
  unsigned short* kvws = (unsigned short*)(ksum + (size_t)NCHUNK * DD);

  hipLaunchKernelGGL(kA_partial, dim3(NCHUNK), dim3(256), 0, stream,
                     k, v, ksum, kvws);
  hipLaunchKernelGGL(kB_out, dim3(NCHUNK), dim3(256), 0, stream,
                     q, k, v, ksum, kvws, out);
}

// Round 9
// 106.863 us; speedup vs baseline: 3.1869x; 1.0557x over previous
//
#include <hip/hip_runtime.h>

// Performer exp-kernel linear causal attention — 3-kernel chain (best of R4)
// + conflict-free staging (best of R8). B=4 H=8 N=2048 D=64 fp32.
// Maxes cancel in the num/denom ratio (verified R4: absmax unchanged).
// k1: per-chunk KV^T partial (bf16) + Ksum      (1024 blocks, MFMA)
// k2: exclusive prefix scan over 32 chunks      (264 blocks, register scan)
// k3: out = (Q'.KVpref + masked(Q'K'^T).V)/den  (1024 blocks, MFMA)
// R5 lesson: cg grid.sync() ~100us on gfx950 — never.
// Staging: one-pass 4x4 register transpose (thread t: j0=4*(t>>4), e4=t&15)
// -> packed b64 LDS writes (R5 measured 2.2M bank-conflict cycles for the
// u16 scatter; R8 verified this fix is value-identical).

#define NSEQ 2048
#define DD 64
#define CH 64
#define NC (NSEQ / CH)   // 32
#define BHN 32
#define NCHUNK (BHN * NC)   // 1024
#define EPSF 1e-8f
#define NRM 0.35355339059327373f   // 64^(-0.25)
#define C1 (NRM * 1.4426950408889634f)   // nrm * log2(e)

typedef short bf16x8 __attribute__((ext_vector_type(8)));
typedef float f32x4 __attribute__((ext_vector_type(4)));

__device__ __forceinline__ unsigned short f2bf(float f) {
  union { float f; unsigned u; } c; c.f = f;
  unsigned u = c.u + 0x7fffu + ((c.u >> 16) & 1u);
  return (unsigned short)(u >> 16);
}
__device__ __forceinline__ float bf2f(unsigned short s) {
  union { unsigned u; float f; } c; c.u = ((unsigned)s) << 16;
  return c.f;
}

// ---------------- k1: per-chunk KV partial (bf16) + Ksum ----------------
__global__ __launch_bounds__(256) void k1_partial(const float* __restrict__ kg,
                                                  const float* __restrict__ vg,
                                                  float* __restrict__ ksum,
                                                  unsigned short* __restrict__ kvws) {
  __shared__ __align__(16) unsigned short Kt[DD * 72];   // K'^T  [e][j]
  __shared__ __align__(16) unsigned short Vt[DD * 72];   // V^T   [f][j]
  const int blk = blockIdx.x;
  const int t = threadIdx.x;
  const size_t base = (size_t)blk * (CH * DD);
  const float4* k4 = (const float4*)(kg + base);
  const float4* v4 = (const float4*)(vg + base);
  // one-pass 4x4 register transpose: rows j0..j0+3, cols e0..e0+3
  {
    const int j0 = (t >> 4) << 2;   // 0..60
    const int e4 = t & 15, e0 = e4 << 2;
    float ka[4][4], va[4][4];
#pragma unroll
    for (int jj = 0; jj < 4; ++jj) {
      float4 kk = k4[(j0 + jj) * 16 + e4];
      float4 vv = v4[(j0 + jj) * 16 + e4];
      ka[jj][0] = exp2f(kk.x * C1) + EPSF;
      ka[jj][1] = exp2f(kk.y * C1) + EPSF;
      ka[jj][2] = exp2f(kk.z * C1) + EPSF;
      ka[jj][3] = exp2f(kk.w * C1) + EPSF;
      va[jj][0] = vv.x; va[jj][1] = vv.y; va[jj][2] = vv.z; va[jj][3] = vv.w;
    }
#pragma unroll
    for (int i = 0; i < 4; ++i) {
      short4 wk, wv;
      wk.x = (short)f2bf(ka[0][i]); wk.y = (short)f2bf(ka[1][i]);
      wk.z = (short)f2bf(ka[2][i]); wk.w = (short)f2bf(ka[3][i]);
      wv.x = (short)f2bf(va[0][i]); wv.y = (short)f2bf(va[1][i]);
      wv.z = (short)f2bf(va[2][i]); wv.w = (short)f2bf(va[3][i]);
      *(short4*)&Kt[(e0 + i) * 72 + j0] = wk;
      *(short4*)&Vt[(e0 + i) * 72 + j0] = wv;
    }
  }
  __syncthreads();
  const int wr = t >> 6, l = t & 63, lg = l >> 4, lc = l & 15;
  // A fragments: rows e = wr*16+lc, k = j
  bf16x8 a0 = *(const bf16x8*)&Kt[(wr * 16 + lc) * 72 + lg * 8];
  bf16x8 a1 = *(const bf16x8*)&Kt[(wr * 16 + lc) * 72 + 32 + lg * 8];
  // Ksum over j of K'[j][e]
  float ks = 0.f;
#pragma unroll
  for (int i = 0; i < 8; ++i) ks += bf2f((unsigned short)a0[i]) + bf2f((unsigned short)a1[i]);
  ks += __shfl_xor(ks, 16, 64);
  ks += __shfl_xor(ks, 32, 64);
  if (lg == 0) ksum[(size_t)blk * DD + wr * 16 + lc] = ks;
  // KV = K'^T @ V
  f32x4 acc[4];
#pragma unroll
  for (int ft = 0; ft < 4; ++ft) acc[ft] = (f32x4){0.f, 0.f, 0.f, 0.f};
#pragma unroll
  for (int ft = 0; ft < 4; ++ft) {
    bf16x8 b0 = *(const bf16x8*)&Vt[(ft * 16 + lc) * 72 + lg * 8];
    bf16x8 b1 = *(const bf16x8*)&Vt[(ft * 16 + lc) * 72 + 32 + lg * 8];
    acc[ft] = __builtin_amdgcn_mfma_f32_16x16x32_bf16(a0, b0, acc[ft], 0, 0, 0);
    acc[ft] = __builtin_amdgcn_mfma_f32_16x16x32_bf16(a1, b1, acc[ft], 0, 0, 0);
  }
  // store ws[blk][f][e] bf16; rows e = wr*16 + lg*4 + reg
  unsigned short* kvb = kvws + (size_t)blk * (DD * DD);
  const int ee0 = wr * 16 + lg * 4;
#pragma unroll
  for (int ft = 0; ft < 4; ++ft) {
    short4 w;
    w.x = (short)f2bf(acc[ft][0]);
    w.y = (short)f2bf(acc[ft][1]);
    w.z = (short)f2bf(acc[ft][2]);
    w.w = (short)f2bf(acc[ft][3]);
    *(short4*)&kvb[(ft * 16 + lc) * DD + ee0] = w;
  }
}

// ---------------- k2: exclusive prefix scan over chunks (register scan) ----------------
// blocks 0..255: kv dword-columns (all 32 loads issued, then scan in regs).
// blocks 256..263: ksum columns.
__global__ __launch_bounds__(256) void k2_scan(float* __restrict__ ksum,
                                               unsigned short* __restrict__ kvws) {
  const int blk = blockIdx.x;
  const int t = threadIdx.x;
  if (blk < 256) {
    const int bh = blk >> 3;
    const int col = (blk & 7) * 256 + t;   // dword col 0..2047
    unsigned* p = (unsigned*)kvws + (size_t)bh * NC * 2048 + col;
    unsigned x[NC];
#pragma unroll
    for (int c = 0; c < NC; ++c) x[c] = p[(size_t)c * 2048];
    float a0 = 0.f, a1 = 0.f;
#pragma unroll
    for (int c = 0; c < NC; ++c) {
      float x0 = bf2f((unsigned short)(x[c] & 0xffffu));
      float x1 = bf2f((unsigned short)(x[c] >> 16));
      p[(size_t)c * 2048] = (unsigned)f2bf(a0) | ((unsigned)f2bf(a1) << 16);
      a0 += x0; a1 += x1;
    }
  } else {
    const int gid = (blk - 256) * 256 + t;   // 0..2047
    const int bh = gid >> 6, e = gid & 63;
    float* pk = ksum + (size_t)bh * NC * DD + e;
    float x[NC];
#pragma unroll
    for (int c = 0; c < NC; ++c) x[c] = pk[(size_t)c * DD];
    float run = 0.f;
#pragma unroll
    for (int c = 0; c < NC; ++c) { pk[(size_t)c * DD] = run; run += x[c]; }
  }
}

// ---------------- k3: output ----------------
__global__ __launch_bounds__(256) void k3_out(const float* __restrict__ qg,
                                              const float* __restrict__ kg,
                                              const float* __restrict__ vg,
                                              const float* __restrict__ ksum,
                                              const unsigned short* __restrict__ kvws,
                                              float* __restrict__ out) {
  __shared__ __align__(16) unsigned short Kb[CH * 72];      // K' row-major [j][e]
  __shared__ __align__(16) unsigned short Vt[DD * 72];      // V^T [f][j]
  __shared__ __align__(16) unsigned short Sl[4][16 * 40];   // per-wave masked S
  const int blk = blockIdx.x;
  const int t = threadIdx.x;
  const size_t base = (size_t)blk * (CH * DD);
  const float4* k4 = (const float4*)(kg + base);
  const float4* v4 = (const float4*)(vg + base);
  // stage K' (row-major, b64) and V^T (register 4x4 transpose, b64)
  {
    const int j0 = (t >> 4) << 2;   // 0..60
    const int e4 = t & 15, e0 = e4 << 2;
    float va[4][4];
#pragma unroll
    for (int jj = 0; jj < 4; ++jj) {
      float4 kk = k4[(j0 + jj) * 16 + e4];
      float4 vv = v4[(j0 + jj) * 16 + e4];
      short4 w;
      w.x = (short)f2bf(exp2f(kk.x * C1) + EPSF);
      w.y = (short)f2bf(exp2f(kk.y * C1) + EPSF);
      w.z = (short)f2bf(exp2f(kk.z * C1) + EPSF);
      w.w = (short)f2bf(exp2f(kk.w * C1) + EPSF);
      *(short4*)&Kb[(j0 + jj) * 72 + e0] = w;
      va[jj][0] = vv.x; va[jj][1] = vv.y; va[jj][2] = vv.z; va[jj][3] = vv.w;
    }
#pragma unroll
    for (int i = 0; i < 4; ++i) {
      short4 wv;
      wv.x = (short)f2bf(va[0][i]); wv.y = (short)f2bf(va[1][i]);
      wv.z = (short)f2bf(va[2][i]); wv.w = (short)f2bf(va[3][i]);
      *(short4*)&Vt[(e0 + i) * 72 + j0] = wv;
    }
  }
  const int wr = t >> 6, l = t & 63, lg = l >> 4, lc = l & 15;
  // Q': row = wr*16+lc, cols kt*32 + lg*8 .. +7
  float qe[2][8];
  const float* qrow = qg + base + (size_t)(wr * 16 + lc) * DD;
#pragma unroll
  for (int kt = 0; kt < 2; ++kt) {
    float4 x = *(const float4*)(qrow + kt * 32 + lg * 8);
    float4 y = *(const float4*)(qrow + kt * 32 + lg * 8 + 4);
    qe[kt][0] = x.x; qe[kt][1] = x.y; qe[kt][2] = x.z; qe[kt][3] = x.w;
    qe[kt][4] = y.x; qe[kt][5] = y.y; qe[kt][6] = y.z; qe[kt][7] = y.w;
  }
  bf16x8 qf[2];
  float dp = 0.f;
  const float* ksp = ksum + (size_t)blk * DD;   // exclusive prefix (k2)
#pragma unroll
  for (int kt = 0; kt < 2; ++kt) {
    float4 s0 = *(const float4*)(ksp + kt * 32 + lg * 8);
    float4 s1 = *(const float4*)(ksp + kt * 32 + lg * 8 + 4);
    float ksv[8] = {s0.x, s0.y, s0.z, s0.w, s1.x, s1.y, s1.z, s1.w};
#pragma unroll
    for (int i = 0; i < 8; ++i) {
      float qv = exp2f(qe[kt][i] * C1) + EPSF;
      dp += qv * (ksv[i] + EPSF);
      qf[kt][i] = (short)f2bf(qv);
    }
  }
  dp += __shfl_xor(dp, 16, 64);
  dp += __shfl_xor(dp, 32, 64);   // full-row q'.(ksum_excl+EPS)
  __syncthreads();

  f32x4 o[4];
#pragma unroll
  for (int ft = 0; ft < 4; ++ft) o[ft] = (f32x4){0.f, 0.f, 0.f, 0.f};

  // O_pref: B fragments direct from global bf16 ws [blk][f][e] (exclusive prefix)
  const unsigned short* kvb = kvws + (size_t)blk * (DD * DD);
#pragma unroll
  for (int kt = 0; kt < 2; ++kt) {
#pragma unroll
    for (int ft = 0; ft < 4; ++ft) {
      bf16x8 b = *(const bf16x8*)(kvb + (ft * 16 + lc) * DD + kt * 32 + lg * 8);
      o[ft] = __builtin_amdgcn_mfma_f32_16x16x32_bf16(qf[kt], b, o[ft], 0, 0, 0);
    }
  }

  // causal intra part
  float rs0 = 0.f, rs1 = 0.f, rs2 = 0.f, rs3 = 0.f;
  const int irow = wr * 16 + lg * 4;   // + reg
  const int ng = (wr >> 1) + 1;
  for (int g = 0; g < ng; ++g) {
#pragma unroll
    for (int c2 = 0; c2 < 2; ++c2) {
      const int ct = 2 * g + c2;
      bf16x8 kb0 = *(const bf16x8*)&Kb[(ct * 16 + lc) * 72 + lg * 8];
      bf16x8 kb1 = *(const bf16x8*)&Kb[(ct * 16 + lc) * 72 + 32 + lg * 8];
      f32x4 s = (f32x4){0.f, 0.f, 0.f, 0.f};
      s = __builtin_amdgcn_mfma_f32_16x16x32_bf16(qf[0], kb0, s, 0, 0, 0);
      s = __builtin_amdgcn_mfma_f32_16x16x32_bf16(qf[1], kb1, s, 0, 0, 0);
      const int j = ct * 16 + lc;
      float v0 = (j <= irow + 0) ? s[0] : 0.f;
      float v1 = (j <= irow + 1) ? s[1] : 0.f;
      float v2 = (j <= irow + 2) ? s[2] : 0.f;
      float v3 = (j <= irow + 3) ? s[3] : 0.f;
      rs0 += v0; rs1 += v1; rs2 += v2; rs3 += v3;
      unsigned short* sl = &Sl[wr][0];
      sl[(lg * 4 + 0) * 40 + c2 * 16 + lc] = f2bf(v0);
      sl[(lg * 4 + 1) * 40 + c2 * 16 + lc] = f2bf(v1);
      sl[(lg * 4 + 2) * 40 + c2 * 16 + lc] = f2bf(v2);
      sl[(lg * 4 + 3) * 40 + c2 * 16 + lc] = f2bf(v3);
    }
    // A fragment of masked S (wave-local; DS pipe in-order within a wave)
    bf16x8 sa = *(const bf16x8*)&Sl[wr][lc * 40 + lg * 8];
#pragma unroll
    for (int ft = 0; ft < 4; ++ft) {
      bf16x8 vb = *(const bf16x8*)&Vt[(ft * 16 + lc) * 72 + g * 32 + lg * 8];
      o[ft] = __builtin_amdgcn_mfma_f32_16x16x32_bf16(sa, vb, o[ft], 0, 0, 0);
    }
  }
#pragma unroll
  for (int m = 1; m < 16; m <<= 1) {
    rs0 += __shfl_xor(rs0, m, 64);
    rs1 += __shfl_xor(rs1, m, 64);
    rs2 += __shfl_xor(rs2, m, 64);
    rs3 += __shfl_xor(rs3, m, 64);
  }
  float rsv[4] = {rs0, rs1, rs2, rs3};
  float* op = out + base;
#pragma unroll
  for (int reg = 0; reg < 4; ++reg) {
    float d = __shfl(dp, lg * 4 + reg, 64) + rsv[reg];
    float dinv = 1.0f / d;
#pragma unroll
    for (int ft = 0; ft < 4; ++ft) {
      op[(size_t)(irow + reg) * DD + ft * 16 + lc] = o[ft][reg] * dinv;
    }
  }
}

extern "C" void kernel_launch(void* const* d_in, const int* in_sizes, int n_in,
                              void* d_out, int out_size, void* d_ws, size_t ws_size,
                              hipStream_t stream) {
  const float* q = (const float*)d_in[0];
  const float* k = (const float*)d_in[1];
  const float* v = (const float*)d_in[2];
  float* out = (float*)d_out;
  // ws layout: ksum[1024*64] f32 | kv bf16 [1024*4096]
  float* ksum = (float*)d_ws;
  unsigned short* kvws = (unsigned short*)(ksum + (size_t)NCHUNK * DD);

  hipLaunchKernelGGL(k1_partial, dim3(NCHUNK), dim3(256), 0, stream,
                     k, v, ksum, kvws);
  hipLaunchKernelGGL(k2_scan, dim3(264), dim3(256), 0, stream, ksum, kvws);
  hipLaunchKernelGGL(k3_out, dim3(NCHUNK), dim3(256), 0, stream,
                     q, k, v, ksum, kvws, out);
}